// Round 2
// baseline (944.508 us; speedup 1.0000x reference)
//
#include <hip/hip_runtime.h>
#include <stdint.h>

// Sizes fixed by the problem
#define TPB 512
#define NPTS 4096
#define NBATCH 8
#define NSAMP 1024
#define KK 32
#define CAP 256
#define MLP_BLOCKS 64          // 64 blocks * 512 thr = 32768 points, 1 pt/thread-wave-coop
#define KNN_GROUPS 23
#define KNN_BLOCKS (KNN_GROUPS * NBATCH)   // 184
#define ROWS_PER_G 179                     // ceil(4096/23)
#define GRID1 (NBATCH + MLP_BLOCKS + KNN_BLOCKS)  // 256 blocks -> 1 per CU, all resident
#define DYN_LDS 111616

// Dynamic LDS layout:
//  FPS : [0,64KB) float4 pts4[4096] ; [64KB,+64B) uint2 cand[2][4]
//  KNN : [0,64KB) pts4 ; [64KB,+16KB) u64 list[8 waves][256]
//  MLP : floats: w1[0,1216) b1[1216,1280) w2i(f2)[1280,9472) b2i[9472,9600)
//        w3i[9600,25984) b3i[25984,26112) ; wave areas 26112 + w*224 (gs32|h1 64|h2 128)

__launch_bounds__(TPB, 2)
__global__ void k1(const float* __restrict__ xyz, const float* __restrict__ feat,
                   const float* __restrict__ w1, const float* __restrict__ b1,
                   const float* __restrict__ w2, const float* __restrict__ b2,
                   const float* __restrict__ w3, const float* __restrict__ b3,
                   float* __restrict__ dout, float* __restrict__ ws_m,
                   unsigned short* __restrict__ ws_idx)
{
    extern __shared__ float S[];
    const int tid = threadIdx.x;
    const int blk = blockIdx.x;

    if (blk < NBATCH) {
        // ------------------------- FPS (one block per batch) -------------------------
        const int b = blk;
        float4* pts4 = (float4*)S;
        const float* xb = xyz + (size_t)b * NPTS * 3;
        for (int j = tid; j < NPTS; j += TPB)
            pts4[j] = make_float4(xb[j*3], xb[j*3+1], xb[j*3+2], 0.f);
        __syncthreads();
        uint2* cand = (uint2*)(S + 16384);
        if (tid < 256) {
            float px[16], py[16], pz[16], dist[16];
            #pragma unroll
            for (int s = 0; s < 16; ++s) {
                float4 p = pts4[tid*16 + s];
                px[s] = p.x; py[s] = p.y; pz[s] = p.z; dist[s] = 1e10f;
            }
            int far = 0;
            float* ox = dout + (size_t)b * NSAMP * 3;
            for (int step = 0; step < NSAMP; ++step) {
                float4 f = pts4[far];
                if (tid == 0) { ox[step*3] = f.x; ox[step*3+1] = f.y; ox[step*3+2] = f.z; }
                float bd = -1.f; int bj = 0;
                #pragma unroll
                for (int s = 0; s < 16; ++s) {
                    // EXACT numpy-f32 arithmetic: no fma contraction, sum = (x2+y2)+z2
                    float dx = __fsub_rn(px[s], f.x);
                    float dy = __fsub_rn(py[s], f.y);
                    float dz = __fsub_rn(pz[s], f.z);
                    float d  = __fadd_rn(__fadd_rn(__fmul_rn(dx,dx), __fmul_rn(dy,dy)),
                                         __fmul_rn(dz,dz));
                    float nd = fminf(dist[s], d);
                    dist[s] = nd;
                    if (nd > bd) { bd = nd; bj = tid*16 + s; }   // strict >: first occurrence
                }
                // wave argmax: u32 max on float bits (dist >= 0), then lowest lane wins ties
                unsigned bits = __float_as_uint(bd);
                #pragma unroll
                for (int off = 32; off; off >>= 1) {
                    unsigned o = __shfl_xor(bits, off);
                    bits = bits > o ? bits : o;
                }
                unsigned long long mask = __ballot(__float_as_uint(bd) == bits);
                int fl = (int)__ffsll(mask) - 1;
                int wj = __shfl(bj, fl);
                int w = tid >> 6;
                if ((tid & 63) == 0) cand[(step & 1)*4 + w] = make_uint2(bits, (unsigned)wj);
                __syncthreads();
                const uint2* c = cand + (step & 1)*4;
                unsigned bb = 0u; int bi = 0;
                #pragma unroll
                for (int q2 = 0; q2 < 4; ++q2) {   // ascending wave -> lowest index on tie
                    uint2 e = c[q2];
                    if (e.x > bb) { bb = e.x; bi = (int)e.y; }
                }
                far = bi;
            }
        } else {
            for (int step = 0; step < NSAMP; ++step) __syncthreads();
        }
    } else if (blk < NBATCH + MLP_BLOCKS) {
        // ------------------------- per-point MLP -> m[b,j] ---------------------------
        for (int i = tid; i < 1216; i += TPB) S[i] = w1[i];
        for (int i = tid; i < 64; i += TPB) S[1216 + i] = b1[i];
        float2* w2i = (float2*)(S + 1280);
        for (int i = tid; i < 64*64; i += TPB) {
            int k = i >> 6, l = i & 63;
            w2i[i] = make_float2(w2[k*128 + l], w2[k*128 + 64 + l]);
        }
        float2* b2i = (float2*)(S + 9472);
        for (int i = tid; i < 64; i += TPB) b2i[i] = make_float2(b2[i], b2[i + 64]);
        float2* w3i = (float2*)(S + 9600);
        for (int i = tid; i < 128*64; i += TPB) {
            int k = i >> 6, l = i & 63;
            w3i[i] = make_float2(w3[k*128 + l], w3[k*128 + 64 + l]);
        }
        float2* b3i = (float2*)(S + 25984);
        for (int i = tid; i < 64; i += TPB) b3i[i] = make_float2(b3[i], b3[i + 64]);
        __syncthreads();
        const int w = tid >> 6, lane = tid & 63;
        float* gs  = S + 26112 + w*224;
        float* h1s = gs + 32;
        float* h2s = gs + 96;
        const int pbase = (blk - NBATCH) * TPB + w*64;
        for (int i = 0; i < 64; ++i) {
            int p = pbase + i;
            int b = p >> 12, j = p & 4095;
            if (lane < 19) {
                float v = (lane < 3) ? xyz[((size_t)(b*NPTS + j))*3 + lane]
                                     : feat[((size_t)(b*NPTS + j))*16 + (lane - 3)];
                gs[lane] = v;
            }
            __syncthreads();
            float acc = S[1216 + lane];
            #pragma unroll
            for (int c = 0; c < 19; ++c) acc = fmaf(gs[c], S[c*64 + lane], acc);
            h1s[lane] = fmaxf(acc, 0.f);
            __syncthreads();
            float2 a2 = b2i[lane];
            #pragma unroll 4
            for (int k = 0; k < 64; ++k) {
                float a = h1s[k];
                float2 wv = w2i[k*64 + lane];
                a2.x = fmaf(a, wv.x, a2.x);
                a2.y = fmaf(a, wv.y, a2.y);
            }
            h2s[lane] = fmaxf(a2.x, 0.f);
            h2s[64 + lane] = fmaxf(a2.y, 0.f);
            __syncthreads();
            float2 a3 = b3i[lane];
            #pragma unroll 4
            for (int k = 0; k < 128; ++k) {
                float a = h2s[k];
                float2 wv = w3i[k*64 + lane];
                a3.x = fmaf(a, wv.x, a3.x);
                a3.y = fmaf(a, wv.y, a3.y);
            }
            float mm = fmaxf(a3.x, a3.y);
            #pragma unroll
            for (int off = 32; off; off >>= 1) mm = fmaxf(mm, __shfl_xor(mm, off));
            if (lane == 0) ws_m[p] = mm;
        }
    } else {
        // ------------------------- exact KNN top-32 per row --------------------------
        const int bb = blk - (NBATCH + MLP_BLOCKS);
        const int b = bb & 7, g = bb >> 3;
        float4* pts4 = (float4*)S;
        const float* xb = xyz + (size_t)b * NPTS * 3;
        for (int j = tid; j < NPTS; j += TPB)
            pts4[j] = make_float4(xb[j*3], xb[j*3+1], xb[j*3+2], 0.f);
        __syncthreads();
        const int w = tid >> 6, lane = tid & 63;
        unsigned long long* list = (unsigned long long*)(S + 16384) + (size_t)w * CAP;
        const unsigned long long laneml = (1ull << lane) - 1ull;
        int rend = (g + 1) * ROWS_PER_G; if (rend > NPTS) rend = NPTS;
        for (int r = g*ROWS_PER_G + w; r < rend; r += 8) {
            float4 q = pts4[r];
            float T = 0.0315f, Tlo = 0.f, Thi = 0.f;
            int hasLo = 0, hasHi = 0, cnt = 0;
            for (int iter = 0; iter < 24; ++iter) {
                cnt = 0;
                for (int t = 0; t < 64; ++t) {
                    int j = t*64 + lane;
                    float4 p = pts4[j];
                    float dx = __fsub_rn(p.x, q.x);
                    float dy = __fsub_rn(p.y, q.y);
                    float dz = __fsub_rn(p.z, q.z);
                    float d2 = __fadd_rn(__fadd_rn(__fmul_rn(dx,dx), __fmul_rn(dy,dy)),
                                         __fmul_rn(dz,dz));
                    bool pred = d2 <= T;
                    unsigned long long mask = __ballot(pred);
                    if (pred) {
                        int pos = cnt + __popcll(mask & laneml);
                        if (pos < CAP)
                            list[pos] = ((unsigned long long)__float_as_uint(d2) << 32) | (unsigned)j;
                    }
                    cnt += __popcll(mask);
                }
                if (cnt >= KK && cnt <= CAP) break;
                if (cnt < KK) { Tlo = T; hasLo = 1; } else { Thi = T; hasHi = 1; }
                if (hasLo && hasHi) T = sqrtf(Tlo * Thi);
                else if (cnt < KK) T *= 3.0f;
                else T *= 0.45f;
            }
            if (cnt > CAP) cnt = CAP;
            __builtin_amdgcn_wave_barrier();
            // exact rank of each candidate among distinct keys (d2bits<<32)|idx:
            // rank < 32 -> its exact slot in ascending (d2, idx) order == top_k order
            unsigned long long kc[4]; unsigned rk[4];
            #pragma unroll
            for (int c = 0; c < 4; ++c) {
                int sl = c*64 + lane;
                kc[c] = (sl < cnt) ? list[sl] : ~0ull;
                rk[c] = 0u;
            }
            for (int i = 0; i < cnt; ++i) {
                unsigned long long kb = list[i];
                #pragma unroll
                for (int c = 0; c < 4; ++c) rk[c] += (kb < kc[c]) ? 1u : 0u;
            }
            unsigned short* orow = ws_idx + ((size_t)(b*NPTS + r)) * KK;
            #pragma unroll
            for (int c = 0; c < 4; ++c) {
                int sl = c*64 + lane;
                if (sl < cnt && rk[c] < KK)
                    orow[rk[c]] = (unsigned short)(kc[c] & 0xffffull);
            }
        }
    }
}

__global__ void k2(const unsigned short* __restrict__ idx16, const float* __restrict__ m,
                   float* __restrict__ outf)
{
    int t = blockIdx.x * 512 + threadIdx.x;   // 2048*512 = 1048576 = 8*4096*32
    int b = t >> 17;                          // 4096*32 = 131072 per batch
    outf[t] = m[b*4096 + (int)idx16[t]];
}

extern "C" void kernel_launch(void* const* d_in, const int* in_sizes, int n_in,
                              void* d_out, int out_size, void* d_ws, size_t ws_size,
                              hipStream_t stream)
{
    const float* xyz  = (const float*)d_in[0];
    const float* feat = (const float*)d_in[1];
    const float* w1   = (const float*)d_in[2];
    const float* b1   = (const float*)d_in[3];
    const float* w2   = (const float*)d_in[4];
    const float* b2   = (const float*)d_in[5];
    const float* w3   = (const float*)d_in[6];
    const float* b3   = (const float*)d_in[7];
    float* dout = (float*)d_out;
    float* ws_m = (float*)d_ws;                                  // 32768 f32
    unsigned short* ws_idx = (unsigned short*)((char*)d_ws + 131072);  // 1M u16

    hipFuncSetAttribute((const void*)k1, hipFuncAttributeMaxDynamicSharedMemorySize, DYN_LDS);

    hipLaunchKernelGGL(k1, dim3(GRID1), dim3(TPB), DYN_LDS, stream,
                       xyz, feat, w1, b1, w2, b2, w3, b3, dout, ws_m, ws_idx);
    hipLaunchKernelGGL(k2, dim3(2048), dim3(512), 0, stream,
                       ws_idx, ws_m, dout + 24576);
}

// Round 3
// 682.099 us; speedup vs baseline: 1.3847x; 1.3847x over previous
//
#include <hip/hip_runtime.h>
#include <stdint.h>

// Sizes fixed by the problem
#define TPB 512
#define NPTS 4096
#define NBATCH 8
#define NSAMP 1024
#define KK 32
#define CAP 256
#define MLP_BLOCKS 64          // 64 blocks * 512 thr = 32768 points
#define KNN_GROUPS 23
#define KNN_BLOCKS (KNN_GROUPS * NBATCH)   // 184
#define ROWS_PER_G 179                     // ceil(4096/23)
#define GRID1 (NBATCH + MLP_BLOCKS + KNN_BLOCKS)  // 256 blocks -> 1 per CU, all resident
#define DYN_LDS 111616

// DPP-based wave64 max reduction on u32 (result valid in lane 63, returned via readlane).
// All lanes must be active. ~6 dependent VALU ops instead of 6 ds_bpermute round-trips.
__device__ __forceinline__ unsigned wave_max_u32(unsigned x) {
    int v = (int)x;
#define DSTEP(ctrl) { int t = __builtin_amdgcn_update_dpp(v, v, ctrl, 0xF, 0xF, false); \
                      v = ((unsigned)v > (unsigned)t) ? v : t; }
    DSTEP(0xB1)   // quad_perm [1,0,3,2]  : xor 1
    DSTEP(0x4E)   // quad_perm [2,3,0,1]  : xor 2
    DSTEP(0x141)  // row_half_mirror      : combine quads within 8
    DSTEP(0x140)  // row_mirror           : combine 8s within 16
    DSTEP(0x142)  // row_bcast15          : lanes 16-31 / 48-63 pick up lower half
    DSTEP(0x143)  // row_bcast31          : lanes 32-63 pick up max(0..31)
#undef DSTEP
    return (unsigned)__builtin_amdgcn_readlane(v, 63);
}

__launch_bounds__(TPB)
__global__ void k1(const float* __restrict__ xyz, const float* __restrict__ feat,
                   const float* __restrict__ w1, const float* __restrict__ b1,
                   const float* __restrict__ w2, const float* __restrict__ b2,
                   const float* __restrict__ w3, const float* __restrict__ b3,
                   float* __restrict__ dout, float* __restrict__ ws_m,
                   unsigned short* __restrict__ ws_idx)
{
    extern __shared__ float S[];
    const int tid = threadIdx.x;
    const int blk = blockIdx.x;

    if (blk < NBATCH) {
        // ------------------------- FPS (one block per batch) -------------------------
        const int b = blk;
        float4* pts4 = (float4*)S;
        const float* xb = xyz + (size_t)b * NPTS * 3;
        for (int j = tid; j < NPTS; j += TPB)
            pts4[j] = make_float4(xb[j*3], xb[j*3+1], xb[j*3+2], 0.f);
        __syncthreads();
        uint2* cand = (uint2*)(S + 16384);
        if (tid < 256) {
            const int base = tid * 16;
            const int lane = tid & 63, w = tid >> 6;
            // 16 points per lane in NAMED scalars -> guaranteed VGPR residency (no spill)
            float4 q_;
#define LDP(i) q_ = pts4[base + i]; \
               float px##i = q_.x, py##i = q_.y, pz##i = q_.z, dd##i = 1e10f;
            LDP(0) LDP(1) LDP(2) LDP(3) LDP(4) LDP(5) LDP(6) LDP(7)
            LDP(8) LDP(9) LDP(10) LDP(11) LDP(12) LDP(13) LDP(14) LDP(15)
#undef LDP
            int far = 0;
            float* ox = dout + (size_t)b * NSAMP * 3;
            for (int step = 0; step < NSAMP; ++step) {
                float4 f = pts4[far];
                if (tid == 0) { ox[step*3] = f.x; ox[step*3+1] = f.y; ox[step*3+2] = f.z; }
                unsigned bb = 0u; int bj = base;
                // EXACT numpy-f32 arithmetic: no fma, sum = (x2+y2)+z2; u32-bit compares
                // (dist >= 0 so IEEE bits are order-preserving); strict > keeps lowest s.
#define UPD(i) { float dx = __fsub_rn(px##i, f.x); \
                 float dy = __fsub_rn(py##i, f.y); \
                 float dz = __fsub_rn(pz##i, f.z); \
                 float d  = __fadd_rn(__fadd_rn(__fmul_rn(dx,dx), __fmul_rn(dy,dy)), \
                                      __fmul_rn(dz,dz)); \
                 dd##i = fminf(dd##i, d); \
                 unsigned nb = __float_as_uint(dd##i); \
                 if (nb > bb) { bb = nb; bj = base + i; } }
                UPD(0) UPD(1) UPD(2) UPD(3) UPD(4) UPD(5) UPD(6) UPD(7)
                UPD(8) UPD(9) UPD(10) UPD(11) UPD(12) UPD(13) UPD(14) UPD(15)
#undef UPD
                // wave argmax: DPP u32 max, then lowest matching lane (= lowest index,
                // since lane ownership blocks are ascending in index)
                unsigned wmax = wave_max_u32(bb);
                unsigned long long mm = __ballot(bb == wmax);
                int fl = (int)__ffsll(mm) - 1;
                if (lane == fl) cand[(step & 1)*4 + w] = make_uint2(wmax, (unsigned)bj);
                __syncthreads();
                const uint4* cc = (const uint4*)(cand + (step & 1)*4);
                uint4 ca = cc[0], cb = cc[1];
                unsigned m0 = ca.x; int fi = (int)ca.y;      // ascending wave order:
                if (ca.z > m0) { m0 = ca.z; fi = (int)ca.w; } // strict > keeps lowest index
                if (cb.x > m0) { m0 = cb.x; fi = (int)cb.y; }
                if (cb.z > m0) { m0 = cb.z; fi = (int)cb.w; }
                far = fi;
            }
        } else {
            for (int step = 0; step < NSAMP; ++step) __syncthreads();
        }
    } else if (blk < NBATCH + MLP_BLOCKS) {
        // ------------------------- per-point MLP -> m[b,j] ---------------------------
        for (int i = tid; i < 1216; i += TPB) S[i] = w1[i];
        for (int i = tid; i < 64; i += TPB) S[1216 + i] = b1[i];
        float2* w2i = (float2*)(S + 1280);
        for (int i = tid; i < 64*64; i += TPB) {
            int k = i >> 6, l = i & 63;
            w2i[i] = make_float2(w2[k*128 + l], w2[k*128 + 64 + l]);
        }
        float2* b2i = (float2*)(S + 9472);
        for (int i = tid; i < 64; i += TPB) b2i[i] = make_float2(b2[i], b2[i + 64]);
        float2* w3i = (float2*)(S + 9600);
        for (int i = tid; i < 128*64; i += TPB) {
            int k = i >> 6, l = i & 63;
            w3i[i] = make_float2(w3[k*128 + l], w3[k*128 + 64 + l]);
        }
        float2* b3i = (float2*)(S + 25984);
        for (int i = tid; i < 64; i += TPB) b3i[i] = make_float2(b3[i], b3[i + 64]);
        __syncthreads();
        const int w = tid >> 6, lane = tid & 63;
        float* gs  = S + 26112 + w*224;
        float* h1s = gs + 32;
        float* h2s = gs + 96;
        const int pbase = (blk - NBATCH) * TPB + w*64;
        for (int i = 0; i < 64; ++i) {
            int p = pbase + i;
            int b = p >> 12, j = p & 4095;
            if (lane < 19) {
                float v = (lane < 3) ? xyz[((size_t)(b*NPTS + j))*3 + lane]
                                     : feat[((size_t)(b*NPTS + j))*16 + (lane - 3)];
                gs[lane] = v;
            }
            __syncthreads();
            float acc = S[1216 + lane];
            #pragma unroll
            for (int c = 0; c < 19; ++c) acc = fmaf(gs[c], S[c*64 + lane], acc);
            h1s[lane] = fmaxf(acc, 0.f);
            __syncthreads();
            float2 a2 = b2i[lane];
            #pragma unroll 4
            for (int k = 0; k < 64; ++k) {
                float a = h1s[k];
                float2 wv = w2i[k*64 + lane];
                a2.x = fmaf(a, wv.x, a2.x);
                a2.y = fmaf(a, wv.y, a2.y);
            }
            h2s[lane] = fmaxf(a2.x, 0.f);
            h2s[64 + lane] = fmaxf(a2.y, 0.f);
            __syncthreads();
            float2 a3 = b3i[lane];
            #pragma unroll 4
            for (int k = 0; k < 128; ++k) {
                float a = h2s[k];
                float2 wv = w3i[k*64 + lane];
                a3.x = fmaf(a, wv.x, a3.x);
                a3.y = fmaf(a, wv.y, a3.y);
            }
            float mm = fmaxf(a3.x, a3.y);
            #pragma unroll
            for (int off = 32; off; off >>= 1) mm = fmaxf(mm, __shfl_xor(mm, off));
            if (lane == 0) ws_m[p] = mm;
        }
    } else {
        // ------------------------- exact KNN top-32 per row --------------------------
        const int bb = blk - (NBATCH + MLP_BLOCKS);
        const int b = bb & 7, g = bb >> 3;
        float4* pts4 = (float4*)S;
        const float* xb = xyz + (size_t)b * NPTS * 3;
        for (int j = tid; j < NPTS; j += TPB)
            pts4[j] = make_float4(xb[j*3], xb[j*3+1], xb[j*3+2], 0.f);
        __syncthreads();
        const int w = tid >> 6, lane = tid & 63;
        unsigned long long* list = (unsigned long long*)(S + 16384) + (size_t)w * CAP;
        const unsigned long long laneml = (1ull << lane) - 1ull;
        int rend = (g + 1) * ROWS_PER_G; if (rend > NPTS) rend = NPTS;
        for (int r = g*ROWS_PER_G + w; r < rend; r += 8) {
            float4 q = pts4[r];
            float T = 0.0315f, Tlo = 0.f, Thi = 0.f;
            int hasLo = 0, hasHi = 0, cnt = 0;
            for (int iter = 0; iter < 24; ++iter) {
                cnt = 0;
                for (int t = 0; t < 64; ++t) {
                    int j = t*64 + lane;
                    float4 p = pts4[j];
                    float dx = __fsub_rn(p.x, q.x);
                    float dy = __fsub_rn(p.y, q.y);
                    float dz = __fsub_rn(p.z, q.z);
                    float d2 = __fadd_rn(__fadd_rn(__fmul_rn(dx,dx), __fmul_rn(dy,dy)),
                                         __fmul_rn(dz,dz));
                    bool pred = d2 <= T;
                    unsigned long long mask = __ballot(pred);
                    if (pred) {
                        int pos = cnt + __popcll(mask & laneml);
                        if (pos < CAP)
                            list[pos] = ((unsigned long long)__float_as_uint(d2) << 32) | (unsigned)j;
                    }
                    cnt += __popcll(mask);
                }
                if (cnt >= KK && cnt <= CAP) break;
                if (cnt < KK) { Tlo = T; hasLo = 1; } else { Thi = T; hasHi = 1; }
                if (hasLo && hasHi) T = sqrtf(Tlo * Thi);
                else if (cnt < KK) T *= 3.0f;
                else T *= 0.45f;
            }
            if (cnt > CAP) cnt = CAP;
            __builtin_amdgcn_wave_barrier();
            // exact rank among keys (d2bits<<32)|idx: rank<32 == top_k slot
            unsigned long long kc[4]; unsigned rk[4];
            #pragma unroll
            for (int c = 0; c < 4; ++c) {
                int sl = c*64 + lane;
                kc[c] = (sl < cnt) ? list[sl] : ~0ull;
                rk[c] = 0u;
            }
            for (int i = 0; i < cnt; ++i) {
                unsigned long long kb = list[i];
                #pragma unroll
                for (int c = 0; c < 4; ++c) rk[c] += (kb < kc[c]) ? 1u : 0u;
            }
            unsigned short* orow = ws_idx + ((size_t)(b*NPTS + r)) * KK;
            #pragma unroll
            for (int c = 0; c < 4; ++c) {
                int sl = c*64 + lane;
                if (sl < cnt && rk[c] < KK)
                    orow[rk[c]] = (unsigned short)(kc[c] & 0xffffull);
            }
        }
    }
}

__global__ void k2(const unsigned short* __restrict__ idx16, const float* __restrict__ m,
                   float* __restrict__ outf)
{
    int t = blockIdx.x * 512 + threadIdx.x;   // 2048*512 = 1048576 = 8*4096*32
    int b = t >> 17;                          // 4096*32 = 131072 per batch
    outf[t] = m[b*4096 + (int)idx16[t]];
}

extern "C" void kernel_launch(void* const* d_in, const int* in_sizes, int n_in,
                              void* d_out, int out_size, void* d_ws, size_t ws_size,
                              hipStream_t stream)
{
    const float* xyz  = (const float*)d_in[0];
    const float* feat = (const float*)d_in[1];
    const float* w1   = (const float*)d_in[2];
    const float* b1   = (const float*)d_in[3];
    const float* w2   = (const float*)d_in[4];
    const float* b2   = (const float*)d_in[5];
    const float* w3   = (const float*)d_in[6];
    const float* b3   = (const float*)d_in[7];
    float* dout = (float*)d_out;
    float* ws_m = (float*)d_ws;                                  // 32768 f32
    unsigned short* ws_idx = (unsigned short*)((char*)d_ws + 131072);  // 1M u16

    hipFuncSetAttribute((const void*)k1, hipFuncAttributeMaxDynamicSharedMemorySize, DYN_LDS);

    hipLaunchKernelGGL(k1, dim3(GRID1), dim3(TPB), DYN_LDS, stream,
                       xyz, feat, w1, b1, w2, b2, w3, b3, dout, ws_m, ws_idx);
    hipLaunchKernelGGL(k2, dim3(2048), dim3(512), 0, stream,
                       ws_idx, ws_m, dout + 24576);
}